// Round 1
// baseline (164.810 us; speedup 1.0000x reference)
//
#include <hip/hip_runtime.h>

#define NN 4096
#define CC 256
#define DQ 32

typedef __attribute__((ext_vector_type(8))) short short8;
typedef __attribute__((ext_vector_type(4))) short short4v;
typedef __attribute__((ext_vector_type(4))) float f32x4;

__device__ __forceinline__ unsigned short f32_to_bf16(float f) {
  unsigned int u = __float_as_uint(f);
  u += 0x7fffu + ((u >> 16) & 1u);   // RNE
  return (unsigned short)(u >> 16);
}

__device__ __forceinline__ void gld16(const void* g, void* l) {
  __builtin_amdgcn_global_load_lds(
      (__attribute__((address_space(1))) void*)(g),
      (__attribute__((address_space(3))) void*)(l), 16, 0, 0);
}

// ---------------- kernel 1: weights/bias convert ----------------
__global__ __launch_bounds__(256) void wconv_kernel(
    const float* qw, const float* kw, const float* vw,
    const float* qb, const float* kb, const float* vb,
    unsigned short* Wcat, float* bcat) {
  int id = blockIdx.x * 256 + threadIdx.x;
  if (id < 320 * 256) {
    int row = id >> 8;
    float v;
    if (row < 32) v = qw[id];
    else if (row < 64) v = kw[id - 32 * 256];
    else v = vw[id - 64 * 256];
    Wcat[id] = f32_to_bf16(v);
  }
  if (id < 320) {
    float v;
    if (id < 32) v = qb[id];
    else if (id < 64) v = kb[id - 32];
    else v = vb[id - 64];
    bcat[id] = v;
  }
}

// ---------------- kernel 2: x [B][C][N] f32 -> xT [B][N][C] bf16 ----------------
__global__ __launch_bounds__(256) void xpose_kernel(const float* x, unsigned short* xbT) {
  int bid = blockIdx.x;
  int b = bid >> 8, cb = (bid >> 6) & 3, nb = bid & 63;
  __shared__ float tile[64][65];
  int lane = threadIdx.x & 63, r4 = threadIdx.x >> 6;
  const float* xp = x + (((size_t)b * CC + cb * 64) * NN) + nb * 64;
#pragma unroll
  for (int p = 0; p < 16; p++) {
    int c = p * 4 + r4;
    tile[c][lane] = xp[(size_t)c * NN + lane];
  }
  __syncthreads();
  unsigned short* dp = xbT + (((size_t)b * NN + nb * 64) * CC) + cb * 64;
#pragma unroll
  for (int p = 0; p < 16; p++) {
    int n = p * 4 + r4;
    dp[(size_t)n * CC + lane] = f32_to_bf16(tile[lane][n]);
  }
}

// ---------------- kernel 3: QKV projection via MFMA ----------------
// D[n][d] = sum_c xT[n][c] * W[d][c];   A = xT rows(n), B = W^T (W row-major)
// Q,K -> [B][N][32] bf16 (+bias). V -> [B][C][N] bf16 via LDS bounce (+bias).
__global__ __launch_bounds__(256) void proj_kernel(
    const unsigned short* xbT, const unsigned short* Wcat, const float* bcat,
    unsigned short* Qt, unsigned short* Kt, unsigned short* V) {
  int bid = blockIdx.x;
  int b = bid >> 6, nb = bid & 63;
  int tid = threadIdx.x, lane = tid & 63, w = tid >> 6;
  int l15 = lane & 15, h = lane >> 4;
  int n0 = nb * 64 + w * 16;
  const unsigned short* xp = xbT + (size_t)b * NN * CC;

  short8 af[8];
#pragma unroll
  for (int ks = 0; ks < 8; ks++)
    af[ks] = *(const short8*)(xp + (size_t)(n0 + l15) * CC + ks * 32 + h * 8);

  f32x4 acc[20];
#pragma unroll
  for (int t = 0; t < 20; t++)
#pragma unroll
    for (int r = 0; r < 4; r++) acc[t][r] = 0.f;

#pragma unroll
  for (int ks = 0; ks < 8; ks++) {
#pragma unroll
    for (int dt = 0; dt < 20; dt++) {
      short8 bfr = *(const short8*)(Wcat + (size_t)(dt * 16 + l15) * CC + ks * 32 + h * 8);
      acc[dt] = __builtin_amdgcn_mfma_f32_16x16x32_bf16(af[ks], bfr, acc[dt], 0, 0, 0);
    }
  }

  // Q (dt 0,1), K (dt 2,3): D lane holds (row n = h*4+r, col d = l15)
  unsigned short* Qtb = Qt + (size_t)b * NN * DQ;
  unsigned short* Ktb = Kt + (size_t)b * NN * DQ;
#pragma unroll
  for (int dt = 0; dt < 4; dt++) {
    float bias = bcat[dt * 16 + l15];
    unsigned short* dst = dt < 2 ? Qtb : Ktb;
    int dd = (dt & 1) * 16 + l15;
#pragma unroll
    for (int r = 0; r < 4; r++) {
      int n = n0 + h * 4 + r;
      dst[(size_t)n * DQ + dd] = f32_to_bf16(acc[dt][r] + bias);
    }
  }

  // V (dt 4..19) through LDS to coalesce the [C][N] store
  __shared__ unsigned short vbuf[CC][64];
#pragma unroll
  for (int dt = 4; dt < 20; dt++) {
    float bias = bcat[dt * 16 + l15];
    int c = (dt - 4) * 16 + l15;
#pragma unroll
    for (int r = 0; r < 4; r++) {
      int nl = w * 16 + h * 4 + r;
      vbuf[c][nl] = f32_to_bf16(acc[dt][r] + bias);
    }
  }
  __syncthreads();
  unsigned short* Vb = V + (size_t)b * CC * NN + nb * 64;
  for (int cc = 0; cc < 64; cc++) {
    int c = w * 64 + cc;
    Vb[(size_t)c * NN + lane] = vbuf[c][lane];
  }
}

// ---------------- kernel 4: flash attention ----------------
// Swapped QK^T: S^T[m][n] = mfma(A=Kt rows m, B=Qt cols n); lane: col n=l15, row m=h*4+r.
// PV: O^T[c][n] = mfma(A=V[c][m], B=P^T[m][n]); same lane layout for rescale/epilogue.
__global__ __launch_bounds__(256) void attn_kernel(
    const unsigned short* Qt, const unsigned short* Kt, const unsigned short* V,
    const float* x, const float* gamma, float* out) {
  int bid = blockIdx.x;
  int b = bid >> 6, nb = bid & 63;
  int tid = threadIdx.x, lane = tid & 63, w = tid >> 6;
  int l15 = lane & 15, h = lane >> 4;
  int n0 = nb * 64 + w * 16;

  const unsigned short* Qtb = Qt + (size_t)b * NN * DQ;
  const unsigned short* Ktb = Kt + (size_t)b * NN * DQ;
  const unsigned short* Vb  = V  + (size_t)b * CC * NN;

  __shared__ __align__(16) unsigned short kbuf[2][64 * 32];   // [m][d], 64B rows, d-slot ^= (m&3)
  __shared__ __align__(16) unsigned short vbuf[2][CC * 64];   // [c][m], 128B rows, m-slot ^= (c&7)
  __shared__ __align__(16) unsigned short pbuf[4][16 * 64];   // per-wave [n][m], 128B rows, slot ^= (n&7)

  short8 qf = *(const short8*)(Qtb + (size_t)(n0 + l15) * DQ + h * 8);

  f32x4 acc[16];
#pragma unroll
  for (int t = 0; t < 16; t++)
#pragma unroll
    for (int r = 0; r < 4; r++) acc[t][r] = 0.f;
  float run_max = -1e30f, rs = 0.f;

  f32x4 zero4;
#pragma unroll
  for (int r = 0; r < 4; r++) zero4[r] = 0.f;

  auto stage = [&](int ci, int bufi) {
    int m0 = ci * 64;
    {
      int m = tid >> 2, sub = tid & 3;                 // K: 4 KB
      int doff = (sub ^ (m & 3)) * 8;                  // source pre-swizzle
      gld16(Ktb + (size_t)(m0 + m) * DQ + doff, (char*)&kbuf[bufi][0] + tid * 16);
    }
#pragma unroll
    for (int it = 0; it < 8; it++) {                   // V: 32 KB
      int idx = it * 256 + tid;
      int c = idx >> 3, sub = idx & 7;
      int moff = (sub ^ (c & 7)) * 8;
      gld16(Vb + (size_t)c * NN + m0 + moff, (char*)&vbuf[bufi][0] + idx * 16);
    }
  };

  stage(0, 0);

  for (int ci = 0; ci < 64; ci++) {
    __syncthreads();                                   // stage(ci) drained
    if (ci + 1 < 64) stage(ci + 1, (ci + 1) & 1);      // prefetch next chunk
    int bufi = ci & 1;
    const char* kb2 = (const char*)&kbuf[bufi][0];
    const char* vb2 = (const char*)&vbuf[bufi][0];
    char* pb = (char*)&pbuf[w][0];

    // QK^T (swapped): 4 subtiles of 16 m
    f32x4 st[4];
#pragma unroll
    for (int s = 0; s < 4; s++) {
      int m = s * 16 + l15;
      int sub = h ^ (m & 3);
      short8 kf = *(const short8*)(kb2 + m * 64 + sub * 16);
      st[s] = __builtin_amdgcn_mfma_f32_16x16x32_bf16(kf, qf, zero4, 0, 0, 0);
    }

    // online softmax over this 64-m chunk (per n = l15; reduce over 4 lanes)
    float cmax = -1e30f;
#pragma unroll
    for (int s = 0; s < 4; s++)
#pragma unroll
      for (int r = 0; r < 4; r++) cmax = fmaxf(cmax, st[s][r]);
    cmax = fmaxf(cmax, __shfl_xor(cmax, 16));
    cmax = fmaxf(cmax, __shfl_xor(cmax, 32));

    if (__any(cmax > run_max)) {                       // rare rescale
      float nm = fmaxf(run_max, cmax);
      float sc = __expf(run_max - nm);
      rs *= sc;
#pragma unroll
      for (int t = 0; t < 16; t++)
#pragma unroll
        for (int r = 0; r < 4; r++) acc[t][r] *= sc;
      run_max = nm;
    }

    float lsum = 0.f;
    unsigned short pu[16];
#pragma unroll
    for (int s = 0; s < 4; s++)
#pragma unroll
      for (int r = 0; r < 4; r++) {
        float p = __expf(st[s][r] - run_max);
        lsum += p;
        pu[s * 4 + r] = f32_to_bf16(p);
      }
    rs += lsum;

    // P -> LDS (b64 per subtile), 16B-slot XOR swizzle by n
#pragma unroll
    for (int s = 0; s < 4; s++) {
      short4v pv;
#pragma unroll
      for (int r = 0; r < 4; r++) pv[r] = (short)pu[s * 4 + r];
      int inner = (s * 32 + h * 8) ^ ((l15 & 7) << 4);
      *(short4v*)(pb + l15 * 128 + inner) = pv;
    }

    // PV: 2 k-passes (32 m each) x 16 c-tiles
#pragma unroll
    for (int p = 0; p < 2; p++) {
      int pinner = (p * 64 + h * 16) ^ ((l15 & 7) << 4);
      short8 pf = *(const short8*)(pb + l15 * 128 + pinner);
#pragma unroll
      for (int ct = 0; ct < 16; ct++) {
        int c = ct * 16 + l15;
        int sub = (p * 4 + h) ^ (c & 7);
        short8 vf = *(const short8*)(vb2 + c * 128 + sub * 16);
        acc[ct] = __builtin_amdgcn_mfma_f32_16x16x32_bf16(vf, pf, acc[ct], 0, 0, 0);
      }
    }
  }

  // epilogue: O/rs, gamma*O + x
  rs += __shfl_xor(rs, 16);
  rs += __shfl_xor(rs, 32);
  float inv = 1.0f / rs;
  float g = gamma[0];
  const float* xb = x + (size_t)b * CC * NN;
  float* ob = out + (size_t)b * CC * NN;
#pragma unroll
  for (int ct = 0; ct < 16; ct++)
#pragma unroll
    for (int r = 0; r < 4; r++) {
      int c = ct * 16 + h * 4 + r;
      size_t off = (size_t)c * NN + n0 + l15;
      ob[off] = g * acc[ct][r] * inv + xb[off];
    }
}

extern "C" void kernel_launch(void* const* d_in, const int* in_sizes, int n_in,
                              void* d_out, int out_size, void* d_ws, size_t ws_size,
                              hipStream_t stream) {
  (void)in_sizes; (void)n_in; (void)out_size; (void)ws_size;
  const float* x  = (const float*)d_in[0];
  const float* qw = (const float*)d_in[1];
  const float* qb = (const float*)d_in[2];
  const float* kw = (const float*)d_in[3];
  const float* kb = (const float*)d_in[4];
  const float* vw = (const float*)d_in[5];
  const float* vb = (const float*)d_in[6];
  const float* gamma = (const float*)d_in[7];
  float* out = (float*)d_out;

  char* ws = (char*)d_ws;
  unsigned short* xbT  = (unsigned short*)(ws);                        // 8 MB
  unsigned short* Wcat = (unsigned short*)(ws + 8388608);              // 160 KB
  float*          bcat = (float*)(ws + 8388608 + 163840);              // 1.25 KB
  unsigned short* Qt   = (unsigned short*)(ws + 8553728);              // 1 MB
  unsigned short* Kt   = (unsigned short*)(ws + 9602304);              // 1 MB
  unsigned short* V    = (unsigned short*)(ws + 10650880);             // 8 MB

  hipLaunchKernelGGL(wconv_kernel, dim3(320), dim3(256), 0, stream,
                     qw, kw, vw, qb, kb, vb, Wcat, bcat);
  hipLaunchKernelGGL(xpose_kernel, dim3(1024), dim3(256), 0, stream, x, xbT);
  hipLaunchKernelGGL(proj_kernel, dim3(256), dim3(256), 0, stream,
                     xbT, Wcat, bcat, Qt, Kt, V);
  hipLaunchKernelGGL(attn_kernel, dim3(256), dim3(256), 0, stream,
                     Qt, Kt, V, x, gamma, out);
}

// Round 3
// 151.878 us; speedup vs baseline: 1.0851x; 1.0851x over previous
//
#include <hip/hip_runtime.h>

#define NN 4096
#define CC 256
#define DQ 32

typedef __attribute__((ext_vector_type(8))) short short8;
typedef __attribute__((ext_vector_type(4))) short short4v;
typedef __attribute__((ext_vector_type(4))) float f32x4;

__device__ __forceinline__ unsigned short f32_to_bf16(float f) {
  unsigned int u = __float_as_uint(f);
  u += 0x7fffu + ((u >> 16) & 1u);   // RNE
  return (unsigned short)(u >> 16);
}

__device__ __forceinline__ float exp2_hw(float f) {
  return __builtin_amdgcn_exp2f(f);   // v_exp_f32: D = 2^S0
}

__device__ __forceinline__ void gld16(const void* g, void* l) {
  __builtin_amdgcn_global_load_lds(
      (__attribute__((address_space(1))) void*)(g),
      (__attribute__((address_space(3))) void*)(l), 16, 0, 0);
}

// ---------------- kernel 1: weights/bias convert ----------------
__global__ __launch_bounds__(256) void wconv_kernel(
    const float* qw, const float* kw, const float* vw,
    const float* qb, const float* kb, const float* vb,
    unsigned short* Wcat, float* bcat) {
  int id = blockIdx.x * 256 + threadIdx.x;
  if (id < 320 * 256) {
    int row = id >> 8;
    float v;
    if (row < 32) v = qw[id];
    else if (row < 64) v = kw[id - 32 * 256];
    else v = vw[id - 64 * 256];
    Wcat[id] = f32_to_bf16(v);
  }
  if (id < 320) {
    float v;
    if (id < 32) v = qb[id];
    else if (id < 64) v = kb[id - 32];
    else v = vb[id - 64];
    bcat[id] = v;
  }
}

// ---------------- kernel 2: x [B][C][N] f32 -> xT [B][N][C] bf16 ----------------
__global__ __launch_bounds__(256) void xpose_kernel(const float* x, unsigned short* xbT) {
  int bid = blockIdx.x;
  int b = bid >> 8, cb = (bid >> 6) & 3, nb = bid & 63;
  __shared__ float tile[64][65];
  int lane = threadIdx.x & 63, r4 = threadIdx.x >> 6;
  const float* xp = x + (((size_t)b * CC + cb * 64) * NN) + nb * 64;
#pragma unroll
  for (int p = 0; p < 16; p++) {
    int c = p * 4 + r4;
    tile[c][lane] = xp[(size_t)c * NN + lane];
  }
  __syncthreads();
  unsigned short* dp = xbT + (((size_t)b * NN + nb * 64) * CC) + cb * 64;
#pragma unroll
  for (int p = 0; p < 16; p++) {
    int n = p * 4 + r4;
    dp[(size_t)n * CC + lane] = f32_to_bf16(tile[lane][n]);
  }
}

// ---------------- kernel 3: QKV projection via MFMA ----------------
// D[n][d] = sum_c xT[n][c] * W[d][c];   A = xT rows(n), B = W^T (W row-major)
// Q,K -> [B][N][32] bf16 (+bias, Q prescaled by log2e). V -> [B][C][N] bf16.
__global__ __launch_bounds__(256) void proj_kernel(
    const unsigned short* xbT, const unsigned short* Wcat, const float* bcat,
    unsigned short* Qt, unsigned short* Kt, unsigned short* V) {
  int bid = blockIdx.x;
  int b = bid >> 6, nb = bid & 63;
  int tid = threadIdx.x, lane = tid & 63, w = tid >> 6;
  int l15 = lane & 15, h = lane >> 4;
  int n0 = nb * 64 + w * 16;
  const unsigned short* xp = xbT + (size_t)b * NN * CC;

  short8 af[8];
#pragma unroll
  for (int ks = 0; ks < 8; ks++)
    af[ks] = *(const short8*)(xp + (size_t)(n0 + l15) * CC + ks * 32 + h * 8);

  f32x4 acc[20];
#pragma unroll
  for (int t = 0; t < 20; t++)
#pragma unroll
    for (int r = 0; r < 4; r++) acc[t][r] = 0.f;

#pragma unroll
  for (int ks = 0; ks < 8; ks++) {
#pragma unroll
    for (int dt = 0; dt < 20; dt++) {
      short8 bfr = *(const short8*)(Wcat + (size_t)(dt * 16 + l15) * CC + ks * 32 + h * 8);
      acc[dt] = __builtin_amdgcn_mfma_f32_16x16x32_bf16(af[ks], bfr, acc[dt], 0, 0, 0);
    }
  }

  // Q (dt 0,1) prescaled by log2(e) so attention softmax can use exp2 directly.
  unsigned short* Qtb = Qt + (size_t)b * NN * DQ;
  unsigned short* Ktb = Kt + (size_t)b * NN * DQ;
#pragma unroll
  for (int dt = 0; dt < 4; dt++) {
    float bias = bcat[dt * 16 + l15];
    float scale = dt < 2 ? 1.44269504f : 1.0f;
    unsigned short* dst = dt < 2 ? Qtb : Ktb;
    int dd = (dt & 1) * 16 + l15;
#pragma unroll
    for (int r = 0; r < 4; r++) {
      int n = n0 + h * 4 + r;
      dst[(size_t)n * DQ + dd] = f32_to_bf16((acc[dt][r] + bias) * scale);
    }
  }

  // V (dt 4..19) through LDS to coalesce the [C][N] store
  __shared__ unsigned short vbuf[CC][64];
#pragma unroll
  for (int dt = 4; dt < 20; dt++) {
    float bias = bcat[dt * 16 + l15];
    int c = (dt - 4) * 16 + l15;
#pragma unroll
    for (int r = 0; r < 4; r++) {
      int nl = w * 16 + h * 4 + r;
      vbuf[c][nl] = f32_to_bf16(acc[dt][r] + bias);
    }
  }
  __syncthreads();
  unsigned short* Vb = V + (size_t)b * CC * NN + nb * 64;
  for (int cc = 0; cc < 64; cc++) {
    int c = w * 64 + cc;
    Vb[(size_t)c * NN + lane] = vbuf[c][lane];
  }
}

// ---------------- kernel 4: flash attention ----------------
// Swapped QK^T: S^T[m][n] = mfma(A=Kt rows m, B=Qt cols n); lane: col n=l15, row m=h*4+r.
// PV: O^T[c][n] = mfma(A=V[c][m], B=P^T[m][n]); same lane layout for rescale/epilogue.
// Triple-buffered staging, counted vmcnt (never drained mid-loop), raw s_barrier.
__global__ __launch_bounds__(256) void attn_kernel(
    const unsigned short* Qt, const unsigned short* Kt, const unsigned short* V,
    const float* x, const float* gamma, float* out) {
  int bid = blockIdx.x;
  // XCD-aware remap: batch b owns XCD pair {2b, 2b+1} (assumes xcd = bid % 8).
  // Per-XCD hot set = one batch's K+V = 2.25 MB < 4 MB L2.
  int b = (bid & 7) >> 1;
  int nb = (bid >> 3) * 2 + (bid & 1);
  int tid = threadIdx.x, lane = tid & 63, w = tid >> 6;
  int l15 = lane & 15, h = lane >> 4;
  int n0 = nb * 64 + w * 16;

  const unsigned short* Qtb = Qt + (size_t)b * NN * DQ;
  const unsigned short* Ktb = Kt + (size_t)b * NN * DQ;
  const unsigned short* Vb  = V  + (size_t)b * CC * NN;

  __shared__ __align__(16) unsigned short kbuf[3][64 * 32];   // [m][d], 64B rows, d-slot ^= (m&3)
  __shared__ __align__(16) unsigned short vbuf[3][CC * 64];   // [c][m], 128B rows, m-slot ^= (c&7)
  __shared__ __align__(16) unsigned short pbuf[4][16 * 64];   // per-wave [n][m], slot ^= (n&7)

  short8 qf = *(const short8*)(Qtb + (size_t)(n0 + l15) * DQ + h * 8);

  f32x4 acc[16];
#pragma unroll
  for (int t = 0; t < 16; t++)
#pragma unroll
    for (int r = 0; r < 4; r++) acc[t][r] = 0.f;
  float run_max = -1e30f, rs = 0.f;

  f32x4 zero4;
#pragma unroll
  for (int r = 0; r < 4; r++) zero4[r] = 0.f;

  auto stage = [&](int ci, int bufi) {
    int m0 = ci * 64;
    {
      int m = tid >> 2, sub = tid & 3;                 // K: 4 KB (1 gld16/thread)
      int doff = (sub ^ (m & 3)) * 8;                  // source pre-swizzle
      gld16(Ktb + (size_t)(m0 + m) * DQ + doff, (char*)&kbuf[bufi][0] + tid * 16);
    }
#pragma unroll
    for (int it = 0; it < 8; it++) {                   // V: 32 KB (8 gld16/thread)
      int idx = it * 256 + tid;
      int c = idx >> 3, sub = idx & 7;
      int moff = (sub ^ (c & 7)) * 8;
      gld16(Vb + (size_t)c * NN + m0 + moff, (char*)&vbuf[bufi][0] + idx * 16);
    }
  };

  stage(0, 0);
  stage(1, 1);

  for (int ci = 0; ci < 64; ci++) {
    // stage(ci) must be complete; stage(ci+1) may stay in flight (9 insts).
    if (ci == 63) asm volatile("s_waitcnt vmcnt(0)");
    else          asm volatile("s_waitcnt vmcnt(9)");
    asm volatile("" ::: "memory");
    __builtin_amdgcn_s_barrier();
    asm volatile("" ::: "memory");
    // Prefetch 2 ahead into the buffer all waves finished reading last iter.
    if (ci + 2 < 64) stage(ci + 2, (ci + 2) % 3);

    int bufi = ci % 3;
    const char* kb2 = (const char*)&kbuf[bufi][0];
    const char* vb2 = (const char*)&vbuf[bufi][0];
    char* pb = (char*)&pbuf[w][0];

    // QK^T (swapped): 4 subtiles of 16 m
    f32x4 st[4];
#pragma unroll
    for (int s = 0; s < 4; s++) {
      int m = s * 16 + l15;
      int sub = h ^ (m & 3);
      short8 kf = *(const short8*)(kb2 + m * 64 + sub * 16);
      st[s] = __builtin_amdgcn_mfma_f32_16x16x32_bf16(kf, qf, zero4, 0, 0, 0);
    }

    // online softmax (log2 domain; Q prescaled by log2e)
    float cmax = -1e30f;
#pragma unroll
    for (int s = 0; s < 4; s++)
#pragma unroll
      for (int r = 0; r < 4; r++) cmax = fmaxf(cmax, st[s][r]);
    cmax = fmaxf(cmax, __shfl_xor(cmax, 16));
    cmax = fmaxf(cmax, __shfl_xor(cmax, 32));

    if (__any(cmax > run_max + 8.0f)) {                // defer-max (T13)
      float nm = fmaxf(run_max, cmax);
      float sc = exp2_hw(run_max - nm);
      rs *= sc;
#pragma unroll
      for (int t = 0; t < 16; t++)
#pragma unroll
        for (int r = 0; r < 4; r++) acc[t][r] *= sc;
      run_max = nm;
    }

    float lsum = 0.f;
    unsigned short pu[16];
#pragma unroll
    for (int s = 0; s < 4; s++)
#pragma unroll
      for (int r = 0; r < 4; r++) {
        float p = exp2_hw(st[s][r] - run_max);
        lsum += p;
        pu[s * 4 + r] = f32_to_bf16(p);
      }
    rs += lsum;

    // P -> LDS (b64 per subtile), 16B-slot XOR swizzle by n
#pragma unroll
    for (int s = 0; s < 4; s++) {
      short4v pv;
#pragma unroll
      for (int r = 0; r < 4; r++) pv[r] = (short)pu[s * 4 + r];
      int inner = (s * 32 + h * 8) ^ ((l15 & 7) << 4);
      *(short4v*)(pb + l15 * 128 + inner) = pv;
    }

    // PV: 2 k-passes (32 m each) x 16 c-tiles
#pragma unroll
    for (int p = 0; p < 2; p++) {
      int pinner = (p * 64 + h * 16) ^ ((l15 & 7) << 4);
      short8 pf = *(const short8*)(pb + l15 * 128 + pinner);
#pragma unroll
      for (int ct = 0; ct < 16; ct++) {
        int c = ct * 16 + l15;
        int sub = (p * 4 + h) ^ (c & 7);
        short8 vf = *(const short8*)(vb2 + c * 128 + sub * 16);
        acc[ct] = __builtin_amdgcn_mfma_f32_16x16x32_bf16(vf, pf, acc[ct], 0, 0, 0);
      }
    }
  }

  // epilogue: O/rs, gamma*O + x
  rs += __shfl_xor(rs, 16);
  rs += __shfl_xor(rs, 32);
  float inv = 1.0f / rs;
  float g = gamma[0];
  const float* xb = x + (size_t)b * CC * NN;
  float* ob = out + (size_t)b * CC * NN;
#pragma unroll
  for (int ct = 0; ct < 16; ct++)
#pragma unroll
    for (int r = 0; r < 4; r++) {
      int c = ct * 16 + h * 4 + r;
      size_t off = (size_t)c * NN + n0 + l15;
      ob[off] = g * acc[ct][r] * inv + xb[off];
    }
}

extern "C" void kernel_launch(void* const* d_in, const int* in_sizes, int n_in,
                              void* d_out, int out_size, void* d_ws, size_t ws_size,
                              hipStream_t stream) {
  (void)in_sizes; (void)n_in; (void)out_size; (void)ws_size;
  const float* x  = (const float*)d_in[0];
  const float* qw = (const float*)d_in[1];
  const float* qb = (const float*)d_in[2];
  const float* kw = (const float*)d_in[3];
  const float* kb = (const float*)d_in[4];
  const float* vw = (const float*)d_in[5];
  const float* vb = (const float*)d_in[6];
  const float* gamma = (const float*)d_in[7];
  float* out = (float*)d_out;

  char* ws = (char*)d_ws;
  unsigned short* xbT  = (unsigned short*)(ws);                        // 8 MB
  unsigned short* Wcat = (unsigned short*)(ws + 8388608);              // 160 KB
  float*          bcat = (float*)(ws + 8388608 + 163840);              // 1.25 KB
  unsigned short* Qt   = (unsigned short*)(ws + 8553728);              // 1 MB
  unsigned short* Kt   = (unsigned short*)(ws + 9602304);              // 1 MB
  unsigned short* V    = (unsigned short*)(ws + 10650880);             // 8 MB

  hipLaunchKernelGGL(wconv_kernel, dim3(320), dim3(256), 0, stream,
                     qw, kw, vw, qb, kb, vb, Wcat, bcat);
  hipLaunchKernelGGL(xpose_kernel, dim3(1024), dim3(256), 0, stream, x, xbT);
  hipLaunchKernelGGL(proj_kernel, dim3(256), dim3(256), 0, stream,
                     xbT, Wcat, bcat, Qt, Kt, V);
  hipLaunchKernelGGL(attn_kernel, dim3(256), dim3(256), 0, stream,
                     Qt, Kt, V, x, gamma, out);
}

// Round 6
// 109.141 us; speedup vs baseline: 1.5101x; 1.3916x over previous
//
#include <hip/hip_runtime.h>

#define NN 4096
#define CC 256
#define DQ 32

typedef __attribute__((ext_vector_type(8))) short short8;
typedef __attribute__((ext_vector_type(4))) short short4v;
typedef __attribute__((ext_vector_type(4))) float f32x4;

__device__ __forceinline__ unsigned short f32_to_bf16(float f) {
  unsigned int u = __float_as_uint(f);
  u += 0x7fffu + ((u >> 16) & 1u);   // RNE
  return (unsigned short)(u >> 16);
}

__device__ __forceinline__ float exp2_hw(float f) {
  return __builtin_amdgcn_exp2f(f);   // v_exp_f32: D = 2^S0
}

__device__ __forceinline__ void gld16(const void* g, void* l) {
  __builtin_amdgcn_global_load_lds(
      (__attribute__((address_space(1))) void*)(g),
      (__attribute__((address_space(3))) void*)(l), 16, 0, 0);
}

// ---------------- kernel 1: weights/bias convert ----------------
__global__ __launch_bounds__(256) void wconv_kernel(
    const float* qw, const float* kw, const float* vw,
    const float* qb, const float* kb, const float* vb,
    unsigned short* Wcat, float* bcat) {
  int id = blockIdx.x * 256 + threadIdx.x;
  if (id < 320 * 256) {
    int row = id >> 8;
    float v;
    if (row < 32) v = qw[id];
    else if (row < 64) v = kw[id - 32 * 256];
    else v = vw[id - 64 * 256];
    Wcat[id] = f32_to_bf16(v);
  }
  if (id < 320) {
    float v;
    if (id < 32) v = qb[id];
    else if (id < 64) v = kb[id - 32];
    else v = vb[id - 64];
    bcat[id] = v;
  }
}

// ---------------- kernel 2: x [B][C][N] f32 -> xT [B][N][C] bf16 ----------------
__global__ __launch_bounds__(256) void xpose_kernel(const float* x, unsigned short* xbT) {
  int bid = blockIdx.x;
  int b = bid >> 8, cb = (bid >> 6) & 3, nb = bid & 63;
  __shared__ float tile[64][65];
  int lane = threadIdx.x & 63, r4 = threadIdx.x >> 6;
  const float* xp = x + (((size_t)b * CC + cb * 64) * NN) + nb * 64;
#pragma unroll
  for (int p = 0; p < 16; p++) {
    int c = p * 4 + r4;
    tile[c][lane] = xp[(size_t)c * NN + lane];
  }
  __syncthreads();
  unsigned short* dp = xbT + (((size_t)b * NN + nb * 64) * CC) + cb * 64;
#pragma unroll
  for (int p = 0; p < 16; p++) {
    int n = p * 4 + r4;
    dp[(size_t)n * CC + lane] = f32_to_bf16(tile[lane][n]);
  }
}

// ---------------- kernel 3: QKV projection via MFMA ----------------
__global__ __launch_bounds__(256) void proj_kernel(
    const unsigned short* xbT, const unsigned short* Wcat, const float* bcat,
    unsigned short* Qt, unsigned short* Kt, unsigned short* V) {
  int bid = blockIdx.x;
  int b = bid >> 6, nb = bid & 63;
  int tid = threadIdx.x, lane = tid & 63, w = tid >> 6;
  int l15 = lane & 15, h = lane >> 4;
  int n0 = nb * 64 + w * 16;
  const unsigned short* xp = xbT + (size_t)b * NN * CC;

  short8 af[8];
#pragma unroll
  for (int ks = 0; ks < 8; ks++)
    af[ks] = *(const short8*)(xp + (size_t)(n0 + l15) * CC + ks * 32 + h * 8);

  f32x4 acc[20];
#pragma unroll
  for (int t = 0; t < 20; t++)
#pragma unroll
    for (int r = 0; r < 4; r++) acc[t][r] = 0.f;

#pragma unroll
  for (int ks = 0; ks < 8; ks++) {
#pragma unroll
    for (int dt = 0; dt < 20; dt++) {
      short8 bfr = *(const short8*)(Wcat + (size_t)(dt * 16 + l15) * CC + ks * 32 + h * 8);
      acc[dt] = __builtin_amdgcn_mfma_f32_16x16x32_bf16(af[ks], bfr, acc[dt], 0, 0, 0);
    }
  }

  // Q (dt 0,1) prescaled by log2(e) so attention softmax can use exp2 directly.
  unsigned short* Qtb = Qt + (size_t)b * NN * DQ;
  unsigned short* Ktb = Kt + (size_t)b * NN * DQ;
#pragma unroll
  for (int dt = 0; dt < 4; dt++) {
    float bias = bcat[dt * 16 + l15];
    float scale = dt < 2 ? 1.44269504f : 1.0f;
    unsigned short* dst = dt < 2 ? Qtb : Ktb;
    int dd = (dt & 1) * 16 + l15;
#pragma unroll
    for (int r = 0; r < 4; r++) {
      int n = n0 + h * 4 + r;
      dst[(size_t)n * DQ + dd] = f32_to_bf16((acc[dt][r] + bias) * scale);
    }
  }

  // V (dt 4..19) through LDS to coalesce the [C][N] store
  __shared__ unsigned short vbuf[CC][64];
#pragma unroll
  for (int dt = 4; dt < 20; dt++) {
    float bias = bcat[dt * 16 + l15];
    int c = (dt - 4) * 16 + l15;
#pragma unroll
    for (int r = 0; r < 4; r++) {
      int nl = w * 16 + h * 4 + r;
      vbuf[c][nl] = f32_to_bf16(acc[dt][r] + bias);
    }
  }
  __syncthreads();
  unsigned short* Vb = V + (size_t)b * CC * NN + nb * 64;
  for (int cc = 0; cc < 64; cc++) {
    int c = w * 64 + cc;
    Vb[(size_t)c * NN + lane] = vbuf[c][lane];
  }
}

// ---------------- kernel 4: flash attention, 8 waves, split-m ----------------
// Waves 0-3 (grp=0): even 64-m chunks; waves 4-7 (grp=1): odd chunks; same q-tiles.
// QK^T from K in registers (L2-direct). V: 4 chunk-buffers = double-buffered
// supersteps, depth-1 prefetch issued right after the barrier (2-phase, safe:
// the target buffers were last read in superstep T-1, all waves past barrier).
__global__ __launch_bounds__(512) void attn_kernel(
    const unsigned short* Qt, const unsigned short* Kt, const unsigned short* V,
    const float* x, const float* gamma, float* out) {
  int bid = blockIdx.x;
  // XCD-aware remap: batch b owns XCD pair {2b, 2b+1} (xcd = bid % 8).
  int b = (bid & 7) >> 1;
  int nb = (bid >> 3) * 2 + (bid & 1);
  int tid = threadIdx.x, lane = tid & 63, w = tid >> 6;
  int grp = w >> 2;                      // 0: even chunks, 1: odd chunks
  int wq = w & 3;                        // q-tile within block
  int l15 = lane & 15, h = lane >> 4;
  int n0 = nb * 64 + wq * 16;

  const unsigned short* Qtb = Qt + (size_t)b * NN * DQ;
  const unsigned short* Ktb = Kt + (size_t)b * NN * DQ;
  const unsigned short* Vb  = V  + (size_t)b * CC * NN;

  __shared__ __align__(16) unsigned short vbuf[4][CC * 64];  // [c][m] 128B rows, 16B-slot ^= (c&7)
  __shared__ __align__(16) unsigned short pbuf[8][16 * 64];  // per-wave P^T, slot ^= (n&7)
  __shared__ float sstat[8][32];

  short8 qf = *(const short8*)(Qtb + (size_t)(n0 + l15) * DQ + h * 8);

  f32x4 acc[16];
#pragma unroll
  for (int t = 0; t < 16; t++)
#pragma unroll
    for (int r = 0; r < 4; r++) acc[t][r] = 0.f;
  float run_max = -1e30f, rs = 0.f;

  f32x4 zero4;
#pragma unroll
  for (int r = 0; r < 4; r++) zero4[r] = 0.f;

  // Stage both chunks (2t, 2t+1) of superstep t: 8 gld16/thread (64 KB).
  auto stageSS = [&](int t) {
#pragma unroll
    for (int ch = 0; ch < 2; ch++) {
      int ck = 2 * t + ch;
      int m0 = ck * 64;
      char* dst = (char*)&vbuf[ck & 3][0];
#pragma unroll
      for (int it = 0; it < 4; it++) {
        int idx = it * 512 + tid;
        int c = idx >> 3, sub = idx & 7;
        int moff = (sub ^ (c & 7)) * 8;
        gld16(Vb + (size_t)c * NN + m0 + moff, dst + idx * 16);
      }
    }
  };

#define KLOAD(T, KF) do { int ci_ = 2 * (T) + grp; \
  _Pragma("unroll") for (int s_ = 0; s_ < 4; s_++) \
    KF[s_] = *(const short8*)(Ktb + (size_t)(ci_ * 64 + s_ * 16 + l15) * DQ + h * 8); \
} while (0)

  short8 kA[4], kB[4];
  stageSS(0);
  KLOAD(0, kA);

// Superstep T: uses K-bank KF; prefetches V(T+1) + K(T+1) into bank KN.
#define SUPERSTEP(T, KF, KN) do { \
  __syncthreads();  /* drains own vm+lgkm, then barrier: stage(T) visible */ \
  if ((T) + 1 < 32) stageSS((T) + 1); \
  f32x4 st[4]; \
  _Pragma("unroll") for (int s = 0; s < 4; s++) \
    st[s] = __builtin_amdgcn_mfma_f32_16x16x32_bf16(KF[s], qf, zero4, 0, 0, 0); \
  if ((T) + 1 < 32) KLOAD((T) + 1, KN); \
  float cmax = -1e30f; \
  _Pragma("unroll") for (int s = 0; s < 4; s++) \
    _Pragma("unroll") for (int r = 0; r < 4; r++) cmax = fmaxf(cmax, st[s][r]); \
  cmax = fmaxf(cmax, __shfl_xor(cmax, 16)); \
  cmax = fmaxf(cmax, __shfl_xor(cmax, 32)); \
  if (__any(cmax > run_max + 8.0f)) { \
    float nm = fmaxf(run_max, cmax); \
    float sc = exp2_hw(run_max - nm); \
    rs *= sc; \
    _Pragma("unroll") for (int t_ = 0; t_ < 16; t_++) \
      _Pragma("unroll") for (int r = 0; r < 4; r++) acc[t_][r] *= sc; \
    run_max = nm; \
  } \
  float lsum = 0.f; \
  unsigned short pu[16]; \
  _Pragma("unroll") for (int s = 0; s < 4; s++) \
    _Pragma("unroll") for (int r = 0; r < 4; r++) { \
      float p = exp2_hw(st[s][r] - run_max); \
      lsum += p; \
      pu[s * 4 + r] = f32_to_bf16(p); \
    } \
  rs += lsum; \
  char* pb = (char*)&pbuf[w][0]; \
  _Pragma("unroll") for (int s = 0; s < 4; s++) { \
    short4v pv; \
    _Pragma("unroll") for (int r = 0; r < 4; r++) pv[r] = (short)pu[s * 4 + r]; \
    int inner = (s * 32 + h * 8) ^ ((l15 & 7) << 4); \
    *(short4v*)(pb + l15 * 128 + inner) = pv; \
  } \
  const char* vb2 = (const char*)&vbuf[(2 * (T) + grp) & 3][0]; \
  __builtin_amdgcn_s_setprio(1); \
  _Pragma("unroll") for (int p = 0; p < 2; p++) { \
    int pinner = (p * 64 + h * 16) ^ ((l15 & 7) << 4); \
    short8 pf = *(const short8*)(pb + l15 * 128 + pinner); \
    _Pragma("unroll") for (int ct = 0; ct < 16; ct++) { \
      int c = ct * 16 + l15; \
      int sub = (p * 4 + h) ^ (c & 7); \
      short8 vf = *(const short8*)(vb2 + c * 128 + sub * 16); \
      acc[ct] = __builtin_amdgcn_mfma_f32_16x16x32_bf16(vf, pf, acc[ct], 0, 0, 0); \
    } \
  } \
  __builtin_amdgcn_s_setprio(0); \
} while (0)

  for (int t2 = 0; t2 < 16; t2++) {
    SUPERSTEP(2 * t2, kA, kB);
    SUPERSTEP(2 * t2 + 1, kB, kA);
  }
#undef SUPERSTEP
#undef KLOAD

  // rs is an h-partial (each lane summed only m = s*16 + h*4 + r).
  // Reduce across the 4 h-lanes sharing the same n BEFORE the merge.
  // (run_max is already uniform across h: cmax was shfl-reduced in-loop.)
  rs += __shfl_xor(rs, 16);
  rs += __shfl_xor(rs, 32);

  // -------- pairwise merge (wave w with w^4), then epilogue --------
  __syncthreads();
  float* sacc = (float*)&vbuf[0][0];   // 8 waves x 8KB = 64KB scratch
  // give the partner the half of c-tiles it will store
  if (grp == 0) {
#pragma unroll
    for (int j = 0; j < 8; j++)
      *(f32x4*)(sacc + (size_t)w * 2048 + j * 256 + lane * 4) = acc[8 + j];
  } else {
#pragma unroll
    for (int j = 0; j < 8; j++)
      *(f32x4*)(sacc + (size_t)w * 2048 + j * 256 + lane * 4) = acc[j];
  }
  if (h == 0) { sstat[w][l15 * 2] = run_max; sstat[w][l15 * 2 + 1] = rs; }
  __syncthreads();

  int pw = w ^ 4;
  float m_p = sstat[pw][l15 * 2], rs_p = sstat[pw][l15 * 2 + 1];
  float nm = fmaxf(run_max, m_p);
  float s_own = exp2_hw(run_max - nm), s_p = exp2_hw(m_p - nm);
  float rstot = rs * s_own + rs_p * s_p;
  float inv = 1.0f / rstot;
  float g = gamma[0];
  const float* xb = x + (size_t)b * CC * NN;
  float* ob = out + (size_t)b * CC * NN;

  if (grp == 0) {
#pragma unroll
    for (int j = 0; j < 8; j++) {
      f32x4 ap = *(const f32x4*)(sacc + (size_t)pw * 2048 + j * 256 + lane * 4);
#pragma unroll
      for (int r = 0; r < 4; r++) {
        int c = j * 16 + h * 4 + r;
        size_t off = (size_t)c * NN + n0 + l15;
        ob[off] = g * (acc[j][r] * s_own + ap[r] * s_p) * inv + xb[off];
      }
    }
  } else {
#pragma unroll
    for (int j = 0; j < 8; j++) {
      f32x4 ap = *(const f32x4*)(sacc + (size_t)pw * 2048 + j * 256 + lane * 4);
#pragma unroll
      for (int r = 0; r < 4; r++) {
        int c = (8 + j) * 16 + h * 4 + r;
        size_t off = (size_t)c * NN + n0 + l15;
        ob[off] = g * (acc[8 + j][r] * s_own + ap[r] * s_p) * inv + xb[off];
      }
    }
  }
}

extern "C" void kernel_launch(void* const* d_in, const int* in_sizes, int n_in,
                              void* d_out, int out_size, void* d_ws, size_t ws_size,
                              hipStream_t stream) {
  (void)in_sizes; (void)n_in; (void)out_size; (void)ws_size;
  const float* x  = (const float*)d_in[0];
  const float* qw = (const float*)d_in[1];
  const float* qb = (const float*)d_in[2];
  const float* kw = (const float*)d_in[3];
  const float* kb = (const float*)d_in[4];
  const float* vw = (const float*)d_in[5];
  const float* vb = (const float*)d_in[6];
  const float* gamma = (const float*)d_in[7];
  float* out = (float*)d_out;

  char* ws = (char*)d_ws;
  unsigned short* xbT  = (unsigned short*)(ws);                        // 8 MB
  unsigned short* Wcat = (unsigned short*)(ws + 8388608);              // 160 KB
  float*          bcat = (float*)(ws + 8388608 + 163840);              // 1.25 KB
  unsigned short* Qt   = (unsigned short*)(ws + 8553728);              // 1 MB
  unsigned short* Kt   = (unsigned short*)(ws + 9602304);              // 1 MB
  unsigned short* V    = (unsigned short*)(ws + 10650880);             // 8 MB

  hipLaunchKernelGGL(wconv_kernel, dim3(320), dim3(256), 0, stream,
                     qw, kw, vw, qb, kb, vb, Wcat, bcat);
  hipLaunchKernelGGL(xpose_kernel, dim3(1024), dim3(256), 0, stream, x, xbT);
  hipLaunchKernelGGL(proj_kernel, dim3(256), dim3(256), 0, stream,
                     xbT, Wcat, bcat, Qt, Kt, V);
  hipLaunchKernelGGL(attn_kernel, dim3(256), dim3(512), 0, stream,
                     Qt, Kt, V, x, gamma, out);
}